// Round 8
// baseline (138.158 us; speedup 1.0000x reference)
//
#include <hip/hip_runtime.h>

#define HW 50176            // 224*224
#define HW4 12544           // HW/4 (float4 / uint2-of-f16x4 per frame)
#define TT 64
#define NB1 1568            // 8 b × 2 tc × 98 hw-blocks (98*256*2 = HW)
#define NB3 3808            // 8 b × 68 t × 7 segs (7*1792 = 12544 = HW4)
#define SUMW 0.9999f        // 0.2989+0.587+0.114

__device__ __forceinline__ float gelu_erf(float x) {
    return 0.5f * x * (1.0f + erff(0.70710678f * x));
}
__device__ __forceinline__ float fast_rcp(float v) {
    float r; asm("v_rcp_f32 %0, %1" : "=v"(r) : "v"(v)); return r;
}
__device__ __forceinline__ float gelu_fast(float x) {
    // tanh-form gelu; max |err| ~3e-3 vs erf (cancels through normalize)
    float x2 = x * x;
    float e = exp2f(-x * fmaf(0.1029433f, x2, 2.3022078f));
    return x * fast_rcp(1.0f + e);
}
__device__ __forceinline__ unsigned encf(float f) {
    unsigned u = __float_as_uint(f);
    return (u & 0x80000000u) ? ~u : (u | 0x80000000u);
}
__device__ __forceinline__ float decf(unsigned u) {
    unsigned b = (u & 0x80000000u) ? (u ^ 0x80000000u) : ~u;
    return __uint_as_float(b);
}
__device__ __forceinline__ unsigned pk_min_f16(unsigned a, unsigned b) {
    unsigned r; asm("v_pk_min_f16 %0, %1, %2" : "=v"(r) : "v"(a), "v"(b)); return r;
}
__device__ __forceinline__ unsigned pack2(float lo, float hi) {
    auto p = __builtin_amdgcn_cvt_pkrtz(lo, hi);
    return __builtin_bit_cast(unsigned, p);
}
__device__ __forceinline__ unsigned pk2(float r) { return pack2(r, -r); }

// Pass 1 (fused): 2 px/thread, chunk of 32 windows (2 chunks cover t=0..63).
// min/max accumulators are 16 NAMED scalars (never an indexable array -> never scratch),
// flushed by wave butterfly every 16 windows. Writes gs = sum_c w_c*gelu(re_c) as 2xf16.
template<int TC, bool WGS>
__global__ __launch_bounds__(256, 5) void k_pass1(const float* __restrict__ x,
                                                  unsigned* __restrict__ gmm,
                                                  _Float16* __restrict__ gs) {
    __shared__ unsigned smin[32], smax[32];
    const int tid = threadIdx.x;
    if (tid < 32) smin[tid] = 0xFFFFFFFFu;
    else if (tid < 64) smax[tid - 32] = 0u;
    __syncthreads();

    const int bid = blockIdx.x;            // < 784 = 8 b × 98 hwb
    const int b   = bid / 98;
    const int hwb = bid - b * 98;
    const int t0  = TC * 32;
    const int hw  = (hwb * 256 + tid) * 2;
    const float* xa = x + ((size_t)(b * 3 + 0) * TT + t0) * (size_t)HW + hw;
    const float* xb = x + ((size_t)(b * 3 + 1) * TT + t0) * (size_t)HW + hw;
    const float* xc = x + ((size_t)(b * 3 + 2) * TT + t0) * (size_t)HW + hw;
    _Float16* gp = gs + ((size_t)b * TT + t0) * (size_t)HW + hw;

    #define LA(f) (*(const float2*)(xa + (size_t)(f) * HW))
    #define LB(f) (*(const float2*)(xb + (size_t)(f) * HW))
    #define LC(f) (*(const float2*)(xc + (size_t)(f) * HW))

    // sliding window (rel frames r..r+4) + 2-deep prefetch, per channel
    float2 a0 = LA(0), a1 = LA(1), a2 = LA(2), a3 = LA(3), a4 = LA(4), pa = LA(5), qa = LA(6);
    float2 b0 = LB(0), b1 = LB(1), b2 = LB(2), b3 = LB(3), b4 = LB(4), pb = LB(5), qb = LB(6);
    float2 c0 = LC(0), c1 = LC(1), c2 = LC(2), c3 = LC(3), c4 = LC(4), pc = LC(5), qc = LC(6);

    const int lane = tid & 63;
    unsigned A0,A1,A2,A3,A4,A5,A6,A7,A8,A9,A10,A11,A12,A13,A14,A15;
    // compile-time-folded lvalue select (j is an unroll constant)
    #define ACC(j) (j==0?A0:j==1?A1:j==2?A2:j==3?A3:j==4?A4:j==5?A5:j==6?A6:j==7?A7: \
                    j==8?A8:j==9?A9:j==10?A10:j==11?A11:j==12?A12:j==13?A13:j==14?A14:A15)

    #pragma unroll
    for (int g = 0; g < 2; ++g) {
        A0=A1=A2=A3=A4=A5=A6=A7=A8=A9=A10=A11=A12=A13=A14=A15=0x7BFF7BFFu;

        #pragma unroll
        for (int j = 0; j < 16; ++j) {
            const int t = t0 + g * 16 + j;          // absolute window index (constant)
            float rax, ray, rbx, rby, rcx, rcy;
            if (t < 60) {                            // weights -4,-2,0,2,4
                rax = fmaf(4.f, a4.x-a0.x, 2.f*(a3.x-a1.x)); ray = fmaf(4.f, a4.y-a0.y, 2.f*(a3.y-a1.y));
                rbx = fmaf(4.f, b4.x-b0.x, 2.f*(b3.x-b1.x)); rby = fmaf(4.f, b4.y-b0.y, 2.f*(b3.y-b1.y));
                rcx = fmaf(4.f, c4.x-c0.x, 2.f*(c3.x-c1.x)); rcy = fmaf(4.f, c4.y-c0.y, 2.f*(c3.y-c1.y));
            } else if (t == 60) {                    // -3,-1,1,3
                rax = fmaf(3.f, a3.x-a0.x, a2.x-a1.x); ray = fmaf(3.f, a3.y-a0.y, a2.y-a1.y);
                rbx = fmaf(3.f, b3.x-b0.x, b2.x-b1.x); rby = fmaf(3.f, b3.y-b0.y, b2.y-b1.y);
                rcx = fmaf(3.f, c3.x-c0.x, c2.x-c1.x); rcy = fmaf(3.f, c3.y-c0.y, c2.y-c1.y);
            } else if (t == 61) {                    // -2,0,2
                rax = 2.f*(a2.x-a0.x); ray = 2.f*(a2.y-a0.y);
                rbx = 2.f*(b2.x-b0.x); rby = 2.f*(b2.y-b0.y);
                rcx = 2.f*(c2.x-c0.x); rcy = 2.f*(c2.y-c0.y);
            } else if (t == 62) {                    // -1,1
                rax = a1.x-a0.x; ray = a1.y-a0.y;
                rbx = b1.x-b0.x; rby = b1.y-b0.y;
                rcx = c1.x-c0.x; rcy = c1.y-c0.y;
            } else {                                 // t=63: weight 0
                rax = ray = rbx = rby = rcx = rcy = 0.f;
            }
            unsigned m = pk_min_f16(
                pk_min_f16(pk_min_f16(pk2(rax), pk2(ray)), pk_min_f16(pk2(rbx), pk2(rby))),
                pk_min_f16(pk2(rcx), pk2(rcy)));
            ACC(j) = pk_min_f16(ACC(j), m);
            if constexpr (WGS) {
                float gx = fmaf(0.114f, gelu_fast(rcx), fmaf(0.587f, gelu_fast(rbx), 0.2989f * gelu_fast(rax)));
                float gy = fmaf(0.114f, gelu_fast(rcy), fmaf(0.587f, gelu_fast(rby), 0.2989f * gelu_fast(ray)));
                *(unsigned*)(gp + (size_t)(g * 16 + j) * HW) = pack2(gx, gy);
            }
            a0=a1; a1=a2; a2=a3; a3=a4; a4=pa; pa=qa;
            b0=b1; b1=b2; b2=b3; b3=b4; b4=pb; pb=qb;
            c0=c1; c1=c2; c2=c3; c3=c4; c4=pc; pc=qc;
            const int rel = g * 16 + j;              // load rel+7 while within chunk range
            if ((TC == 0 && rel <= 28) || (TC == 1 && rel <= 24)) {
                qa = LA(rel + 7); qb = LB(rel + 7); qc = LC(rel + 7);
            }
        }

        // flush group g: butterfly each named acc; lane j keeps window t0+16g+j
        unsigned keep = 0x7BFF7BFFu;
        #define BFLY(A, J) { unsigned v = A; \
            v = pk_min_f16(v, (unsigned)__shfl_xor((int)v, 32, 64)); \
            v = pk_min_f16(v, (unsigned)__shfl_xor((int)v, 16, 64)); \
            v = pk_min_f16(v, (unsigned)__shfl_xor((int)v,  8, 64)); \
            v = pk_min_f16(v, (unsigned)__shfl_xor((int)v,  4, 64)); \
            v = pk_min_f16(v, (unsigned)__shfl_xor((int)v,  2, 64)); \
            v = pk_min_f16(v, (unsigned)__shfl_xor((int)v,  1, 64)); \
            if (lane == (J)) keep = v; }
        BFLY(A0,0)  BFLY(A1,1)  BFLY(A2,2)  BFLY(A3,3)
        BFLY(A4,4)  BFLY(A5,5)  BFLY(A6,6)  BFLY(A7,7)
        BFLY(A8,8)  BFLY(A9,9)  BFLY(A10,10) BFLY(A11,11)
        BFLY(A12,12) BFLY(A13,13) BFLY(A14,14) BFLY(A15,15)
        #undef BFLY

        if (lane < 16) {
            union { unsigned u; _Float16 h[2]; } cv; cv.u = keep;
            const float amin = (float)cv.h[0];
            const float amax = -(float)cv.h[1];
            const float g0 = gelu_erf(amin), g1 = gelu_erf(amax);
            const float gmax = fmaxf(g0, g1);
            const float XSTAR = -0.7517916f;         // argmin of gelu
            float gmin;
            if (amin >= XSTAR)      gmin = g0;
            else if (amax <= XSTAR) gmin = g1;
            else                    gmin = fminf(gelu_erf(XSTAR), fminf(g0, g1));
            atomicMin(&smin[g * 16 + lane], encf(gmin));
            atomicMax(&smax[g * 16 + lane], encf(gmax));
        }
    }
    #undef ACC
    #undef LA
    #undef LB
    #undef LC

    __syncthreads();
    if (tid < 32)            atomicMin(&gmm[t0 + tid], smin[tid]);
    else if (tid < 64)       atomicMax(&gmm[TT + t0 + tid - 32], smax[tid - 32]);
}

// Pass 3: out[b,t] = (t<4) ? 0 : gs[b,t-4]*A + B, A/B derived from gmm inline.
__global__ __launch_bounds__(256) void k_pass3(const unsigned* __restrict__ gs,
                                               const unsigned* __restrict__ gmm,
                                               float* __restrict__ out) {
    const int bid = blockIdx.x;
    const int b   = bid / 476;             // 476 = 68*7
    const int r   = bid - b * 476;
    const int t   = r / 7;
    const int seg = r - t * 7;
    const int base4 = seg * 1792 + threadIdx.x;    // float4 index within frame
    float4* op = (float4*)out + ((size_t)b * 68 + t) * HW4 + base4;

    if (t < 4) {
        float4 z = make_float4(0.f, 0.f, 0.f, 0.f);
        #pragma unroll
        for (int k = 0; k < 7; ++k) op[k * 256] = z;
        return;
    }
    const int tm = t - 4;
    const float mn = decf(gmm[tm]);
    const float mx = decf(gmm[TT + tm]) - mn;
    const float inv = fast_rcp((mx != 0.f) ? mx : 1e-5f);
    const float A = inv, Bv = -mn * SUMW * inv;

    const uint2* gpp = (const uint2*)gs + ((size_t)b * TT + tm) * HW4 + base4;
    #pragma unroll
    for (int k = 0; k < 7; ++k) {
        uint2 v = gpp[k * 256];
        union { unsigned u; _Float16 h[2]; } lo, hi; lo.u = v.x; hi.u = v.y;
        float4 o;
        o.x = fmaf((float)lo.h[0], A, Bv);
        o.y = fmaf((float)lo.h[1], A, Bv);
        o.z = fmaf((float)hi.h[0], A, Bv);
        o.w = fmaf((float)hi.h[1], A, Bv);
        op[k * 256] = o;
    }
}

// Fallback helpers (ws too small for gs): consts kernel + direct erf pass
__global__ void k_consts(const unsigned* __restrict__ gmm, float* __restrict__ ab) {
    int t = threadIdx.x;                       // 64 threads
    float mn = decf(gmm[t]);
    float mx = decf(gmm[TT + t]) - mn;
    float inv = 1.0f / ((mx != 0.0f) ? mx : 1e-5f);
    ab[t]      = inv;
    ab[TT + t] = -mn * SUMW * inv;
}

__global__ __launch_bounds__(256) void k_pass2_direct(const float* __restrict__ x,
                                                      const float* __restrict__ ab,
                                                      float* __restrict__ out) {
    __shared__ float sA[TT], sB[TT];
    const int tid = threadIdx.x;
    if (tid < TT)          sA[tid] = ab[tid];
    else if (tid < 2 * TT) sB[tid - TT] = ab[tid];
    __syncthreads();

    const int pix = blockIdx.x * 256 + tid;    // < 401408 = 8*HW
    const int b  = pix / HW;
    const int hw = pix - b * HW;
    const float* x0 = x + (size_t)(b * 3) * (TT * (size_t)HW) + hw;
    const float* x1 = x0 + (size_t)TT * HW;
    const float* x2 = x1 + (size_t)TT * HW;
    float* op = out + (size_t)b * (68 * (size_t)HW) + hw;

    op[0] = 0.f; op[HW] = 0.f; op[2 * (size_t)HW] = 0.f; op[3 * (size_t)HW] = 0.f;
    op += 4 * (size_t)HW;

    float a0 = x0[0], a1 = x0[HW], a2 = x0[2*HW], a3 = x0[3*HW], a4 = x0[4*HW];
    float b0 = x1[0], b1 = x1[HW], b2 = x1[2*HW], b3 = x1[3*HW], b4 = x1[4*HW];
    float c0 = x2[0], c1 = x2[HW], c2 = x2[2*HW], c3 = x2[3*HW], c4 = x2[4*HW];

    auto emit = [&](int t, float ra, float rb, float rc) {
        float gsv = 0.2989f * gelu_erf(ra) + 0.587f * gelu_erf(rb) + 0.114f * gelu_erf(rc);
        op[(size_t)t * HW] = fmaf(gsv, sA[t], sB[t]);
    };

    for (int t = 0; t < 59; ++t) {
        emit(t, 4.f*(a4-a0) + 2.f*(a3-a1), 4.f*(b4-b0) + 2.f*(b3-b1), 4.f*(c4-c0) + 2.f*(c3-c1));
        a0=a1; a1=a2; a2=a3; a3=a4; a4 = x0[(size_t)(t+5)*HW];
        b0=b1; b1=b2; b2=b3; b3=b4; b4 = x1[(size_t)(t+5)*HW];
        c0=c1; c1=c2; c2=c3; c3=c4; c4 = x2[(size_t)(t+5)*HW];
    }
    emit(59, 4.f*(a4-a0) + 2.f*(a3-a1), 4.f*(b4-b0) + 2.f*(b3-b1), 4.f*(c4-c0) + 2.f*(c3-c1));
    a0=a1; a1=a2; a2=a3; a3=a4; b0=b1; b1=b2; b2=b3; b3=b4; c0=c1; c1=c2; c2=c3; c3=c4;
    emit(60, 3.f*(a3-a0) + (a2-a1), 3.f*(b3-b0) + (b2-b1), 3.f*(c3-c0) + (c2-c1));
    a0=a1; a1=a2; a2=a3; b0=b1; b1=b2; b2=b3; c0=c1; c1=c2; c2=c3;
    emit(61, 2.f*(a2-a0), 2.f*(b2-b0), 2.f*(c2-c0));
    a0=a1; a1=a2; b0=b1; b1=b2; c0=c1; c1=c2;
    emit(62, a1-a0, b1-b0, c1-c0);
    op[63 * (size_t)HW] = sB[63];
}

extern "C" void kernel_launch(void* const* d_in, const int* in_sizes, int n_in,
                              void* d_out, int out_size, void* d_ws, size_t ws_size,
                              hipStream_t stream) {
    const float* x = (const float*)d_in[0];
    float* out = (float*)d_out;
    unsigned* gmm = (unsigned*)d_ws;                       // 128 u32
    float* ab = (float*)d_ws + 128;                        // 128 f32 (fallback only)
    _Float16* gs = (_Float16*)((char*)d_ws + 1024);
    const size_t need = 1024 + (size_t)8 * TT * (size_t)HW * 2;   // ~51.4 MB

    // init gmm: 0xFF.. == encoded +inf (min half), 0x00.. < all encodings (max half)
    hipMemsetAsync(gmm, 0xFF, TT * sizeof(unsigned), stream);
    hipMemsetAsync(gmm + TT, 0x00, TT * sizeof(unsigned), stream);

    if (ws_size >= need) {
        k_pass1<0, true><<<NB1 / 2, 256, 0, stream>>>(x, gmm, gs);
        k_pass1<1, true><<<NB1 / 2, 256, 0, stream>>>(x, gmm, gs);
        k_pass3<<<NB3, 256, 0, stream>>>((const unsigned*)gs, gmm, out);
    } else {
        k_pass1<0, false><<<NB1 / 2, 256, 0, stream>>>(x, gmm, nullptr);
        k_pass1<1, false><<<NB1 / 2, 256, 0, stream>>>(x, gmm, nullptr);
        k_consts<<<1, 64, 0, stream>>>(gmm, ab);
        k_pass2_direct<<<1568, 256, 0, stream>>>(x, ab, out);
    }
}

// Round 9
// 132.554 us; speedup vs baseline: 1.0423x; 1.0423x over previous
//
#include <hip/hip_runtime.h>
#include <hip/hip_cooperative_groups.h>

namespace cg = cooperative_groups;

#define HW 50176            // 224*224
#define HW2 25088
#define HW4 12544
#define TT 64
#define SUMW 0.9999f        // 0.2989+0.587+0.114

__device__ __forceinline__ float gelu_erf(float x) {
    return 0.5f * x * (1.0f + erff(0.70710678f * x));
}
__device__ __forceinline__ float fast_rcp(float v) {
    float r; asm("v_rcp_f32 %0, %1" : "=v"(r) : "v"(v)); return r;
}
__device__ __forceinline__ float gelu_fast(float x) {
    // tanh-form gelu; max |err| ~3e-3 vs erf (cancels through normalize)
    float x2 = x * x;
    float e = exp2f(-x * fmaf(0.1029433f, x2, 2.3022078f));
    return x * fast_rcp(1.0f + e);
}
__device__ __forceinline__ unsigned encf(float f) {
    unsigned u = __float_as_uint(f);
    return (u & 0x80000000u) ? ~u : (u | 0x80000000u);
}
__device__ __forceinline__ float decf(unsigned u) {
    unsigned b = (u & 0x80000000u) ? (u ^ 0x80000000u) : ~u;
    return __uint_as_float(b);
}
__device__ __forceinline__ unsigned pk_min_f16(unsigned a, unsigned b) {
    unsigned r; asm("v_pk_min_f16 %0, %1, %2" : "=v"(r) : "v"(a), "v"(b)); return r;
}
__device__ __forceinline__ unsigned pack2(float lo, float hi) {
    auto p = __builtin_amdgcn_cvt_pkrtz(lo, hi);
    return __builtin_bit_cast(unsigned, p);
}
__device__ __forceinline__ unsigned pk2(float r) { return pack2(r, -r); }
__device__ __forceinline__ unsigned mm2(float2 r) {
    return pk_min_f16(pk2(r.x), pk2(r.y));
}
__device__ __forceinline__ float2 re_full2(float2 w0, float2 w1, float2 w3, float2 w4) {
    float2 r;
    r.x = fmaf(4.f, w4.x - w0.x, 2.f * (w3.x - w1.x));
    r.y = fmaf(4.f, w4.y - w0.y, 2.f * (w3.y - w1.y));
    return r;
}

// ============================ COOPERATIVE single-kernel path ==================
// 1 px/thread. Phase A: stream 64 frames x 3ch, track f16 min/max of re,
// keep gs[t] in 32 packed-f16 registers. grid.sync. Phase C: normalize from regs.
__global__ __launch_bounds__(256, 7) void k_fused(const float* __restrict__ x,
                                                  unsigned* __restrict__ gmm,
                                                  float* __restrict__ out) {
    __shared__ unsigned smin[TT], smax[TT];
    __shared__ float sA[TT], sB[TT];
    const int tid = threadIdx.x;
    if (tid < TT) smin[tid] = 0xFFFFFFFFu;
    else if (tid < 2 * TT) smax[tid - TT] = 0u;
    __syncthreads();

    const int px = blockIdx.x * 256 + tid;    // < 401408 = 8*HW
    const int b  = px / HW;
    const int hw = px - b * HW;
    const float* xa = x + ((size_t)(b * 3 + 0) * TT) * (size_t)HW + hw;
    const float* xb = x + ((size_t)(b * 3 + 1) * TT) * (size_t)HW + hw;
    const float* xc = x + ((size_t)(b * 3 + 2) * TT) * (size_t)HW + hw;

    // gs registers: 32 named u32, each = packed f16 (gs[2i], gs[2i+1])
    unsigned G0,G1,G2,G3,G4,G5,G6,G7,G8,G9,G10,G11,G12,G13,G14,G15,
             G16,G17,G18,G19,G20,G21,G22,G23,G24,G25,G26,G27,G28,G29,G30,G31;
    #define GREG(i) (i==0?G0:i==1?G1:i==2?G2:i==3?G3:i==4?G4:i==5?G5:i==6?G6:i==7?G7: \
                     i==8?G8:i==9?G9:i==10?G10:i==11?G11:i==12?G12:i==13?G13:i==14?G14:i==15?G15: \
                     i==16?G16:i==17?G17:i==18?G18:i==19?G19:i==20?G20:i==21?G21:i==22?G22:i==23?G23: \
                     i==24?G24:i==25?G25:i==26?G26:i==27?G27:i==28?G28:i==29?G29:i==30?G30:G31)
    // min/max accumulators: 8 named u32, reused per 8-window group
    unsigned A0,A1,A2,A3,A4,A5,A6,A7;
    #define ACC(j) (j==0?A0:j==1?A1:j==2?A2:j==3?A3:j==4?A4:j==5?A5:j==6?A6:A7)

    // sliding window: frames t..t+4 in a0..a4, 1-deep prefetch pa = t+5
    float a0 = xa[0], a1 = xa[HW], a2 = xa[2*(size_t)HW], a3 = xa[3*(size_t)HW], a4 = xa[4*(size_t)HW], pa = xa[5*(size_t)HW];
    float b0 = xb[0], b1 = xb[HW], b2 = xb[2*(size_t)HW], b3 = xb[3*(size_t)HW], b4 = xb[4*(size_t)HW], pb = xb[5*(size_t)HW];
    float c0 = xc[0], c1 = xc[HW], c2 = xc[2*(size_t)HW], c3 = xc[3*(size_t)HW], c4 = xc[4*(size_t)HW], pc = xc[5*(size_t)HW];

    const int lane = tid & 63;
    float gprev = 0.f;

    #pragma unroll
    for (int g = 0; g < 8; ++g) {
        A0=A1=A2=A3=A4=A5=A6=A7=0x7BFF7BFFu;   // (65504, 65504)

        #pragma unroll
        for (int j = 0; j < 8; ++j) {
            const int t = g * 8 + j;           // compile-time constant
            float ra, rb, rc;
            if (t < 60) {                      // weights -4,-2,0,2,4
                ra = fmaf(4.f, a4 - a0, 2.f * (a3 - a1));
                rb = fmaf(4.f, b4 - b0, 2.f * (b3 - b1));
                rc = fmaf(4.f, c4 - c0, 2.f * (c3 - c1));
            } else if (t == 60) {              // -3,-1,1,3
                ra = fmaf(3.f, a3 - a0, a2 - a1);
                rb = fmaf(3.f, b3 - b0, b2 - b1);
                rc = fmaf(3.f, c3 - c0, c2 - c1);
            } else if (t == 61) {              // -2,0,2
                ra = 2.f * (a2 - a0); rb = 2.f * (b2 - b0); rc = 2.f * (c2 - c0);
            } else if (t == 62) {              // -1,1
                ra = a1 - a0; rb = b1 - b0; rc = c1 - c0;
            } else {                           // t=63: weight 0
                ra = rb = rc = 0.f;
            }
            ACC(j) = pk_min_f16(ACC(j), pk_min_f16(pk_min_f16(pk2(ra), pk2(rb)), pk2(rc)));
            float gg = fmaf(0.114f, gelu_fast(rc),
                       fmaf(0.587f, gelu_fast(rb), 0.2989f * gelu_fast(ra)));
            if (t & 1) GREG(t >> 1) = pack2(gprev, gg);
            else       gprev = gg;
            a0=a1; a1=a2; a2=a3; a3=a4; a4=pa;
            b0=b1; b1=b2; b2=b3; b3=b4; b4=pb;
            c0=c1; c1=c2; c2=c3; c3=c4; c4=pc;
            if (t < 58) {
                pa = xa[(size_t)(t + 6) * HW];
                pb = xb[(size_t)(t + 6) * HW];
                pc = xc[(size_t)(t + 6) * HW];
            }
        }

        // flush group g: butterfly; lane j keeps window g*8+j
        unsigned keep = 0x7BFF7BFFu;
        #define BFLY(A, J) { unsigned v = A; \
            v = pk_min_f16(v, (unsigned)__shfl_xor((int)v, 32, 64)); \
            v = pk_min_f16(v, (unsigned)__shfl_xor((int)v, 16, 64)); \
            v = pk_min_f16(v, (unsigned)__shfl_xor((int)v,  8, 64)); \
            v = pk_min_f16(v, (unsigned)__shfl_xor((int)v,  4, 64)); \
            v = pk_min_f16(v, (unsigned)__shfl_xor((int)v,  2, 64)); \
            v = pk_min_f16(v, (unsigned)__shfl_xor((int)v,  1, 64)); \
            if (lane == (J)) keep = v; }
        BFLY(A0,0) BFLY(A1,1) BFLY(A2,2) BFLY(A3,3)
        BFLY(A4,4) BFLY(A5,5) BFLY(A6,6) BFLY(A7,7)
        #undef BFLY

        if (lane < 8) {
            union { unsigned u; _Float16 h[2]; } cv; cv.u = keep;
            const float amin = (float)cv.h[0];
            const float amax = -(float)cv.h[1];
            const float g0 = gelu_erf(amin), g1 = gelu_erf(amax);
            const float gmax = fmaxf(g0, g1);
            const float XSTAR = -0.7517916f;   // argmin of gelu
            float gmin;
            if (amin >= XSTAR)      gmin = g0;
            else if (amax <= XSTAR) gmin = g1;
            else                    gmin = fminf(gelu_erf(XSTAR), fminf(g0, g1));
            atomicMin(&smin[g * 8 + lane], encf(gmin));
            atomicMax(&smax[g * 8 + lane], encf(gmax));
        }
    }
    #undef ACC

    __syncthreads();
    if (tid < TT)            atomicMin(&gmm[tid], smin[tid]);
    else if (tid < 2 * TT)   atomicMax(&gmm[TT + tid - TT], smax[tid - TT]);

    cg::this_grid().sync();

    // Phase C: derive A/B per t (agent-scope loads -> coherent), apply from registers.
    if (tid < TT) {
        unsigned mnu = __hip_atomic_load(&gmm[tid],      __ATOMIC_RELAXED, __HIP_MEMORY_SCOPE_AGENT);
        unsigned mxu = __hip_atomic_load(&gmm[TT + tid], __ATOMIC_RELAXED, __HIP_MEMORY_SCOPE_AGENT);
        float mn = decf(mnu);
        float mx = decf(mxu) - mn;
        float inv = fast_rcp((mx != 0.f) ? mx : 1e-5f);
        sA[tid] = inv;
        sB[tid] = -mn * SUMW * inv;
    }
    __syncthreads();

    float* op = out + (size_t)b * (68 * (size_t)HW) + hw;
    op[0] = 0.f; op[HW] = 0.f; op[2 * (size_t)HW] = 0.f; op[3 * (size_t)HW] = 0.f;
    op += 4 * (size_t)HW;
    #pragma unroll
    for (int i = 0; i < 32; ++i) {
        union { unsigned u; _Float16 h[2]; } cv; cv.u = GREG(i);
        op[(size_t)(2 * i)     * HW] = fmaf((float)cv.h[0], sA[2 * i],     sB[2 * i]);
        op[(size_t)(2 * i + 1) * HW] = fmaf((float)cv.h[1], sA[2 * i + 1], sB[2 * i + 1]);
    }
    #undef GREG
}

// ============================ FALLBACK: round-5 three-kernel path =============
template<bool WGS>
__global__ __launch_bounds__(256, 6) void k_pass1(const float* __restrict__ x,
                                                  unsigned* __restrict__ gmm,
                                                  unsigned* __restrict__ gs) {
    __shared__ unsigned smin[16], smax[16];
    const int tid = threadIdx.x;
    if (tid < 16) { smin[tid] = 0xFFFFFFFFu; smax[tid] = 0u; }
    __syncthreads();

    const int bid = blockIdx.x;
    const int b   = bid / 392;
    const int rem = bid - b * 392;
    const int tc  = rem / 98;
    const int hwb = rem - tc * 98;
    const int t0  = tc * 16;
    const int hw  = (hwb * 256 + tid) * 2;
    const float* xa = x + ((size_t)(b * 3 + 0) * TT + t0) * (size_t)HW + hw;
    const float* xb = x + ((size_t)(b * 3 + 1) * TT + t0) * (size_t)HW + hw;
    const float* xc = x + ((size_t)(b * 3 + 2) * TT + t0) * (size_t)HW + hw;
    unsigned* gp = gs + ((size_t)b * TT + t0) * (size_t)HW2 + (hwb * 256 + tid);

    unsigned acc[16];
    #pragma unroll
    for (int j = 0; j < 16; ++j) acc[j] = 0x7BFF7BFFu;

    #define LDA(f) (*(const float2*)(xa + (size_t)(f) * HW))
    #define LDB(f) (*(const float2*)(xb + (size_t)(f) * HW))
    #define LDC(f) (*(const float2*)(xc + (size_t)(f) * HW))

    auto step = [&](float2 ra, float2 rb, float2 rc, int j) {
        acc[j] = pk_min_f16(acc[j], pk_min_f16(pk_min_f16(mm2(ra), mm2(rb)), mm2(rc)));
        if constexpr (WGS) {
            float gx = fmaf(0.114f, gelu_fast(rc.x), fmaf(0.587f, gelu_fast(rb.x), 0.2989f * gelu_fast(ra.x)));
            float gy = fmaf(0.114f, gelu_fast(rc.y), fmaf(0.587f, gelu_fast(rb.y), 0.2989f * gelu_fast(ra.y)));
            gp[(size_t)j * HW2] = pack2(gx, gy);
        }
    };

    float2 a0 = LDA(0), a1 = LDA(1), a2 = LDA(2), a3 = LDA(3), a4 = LDA(4), pa = LDA(5);
    float2 b0 = LDB(0), b1 = LDB(1), b2 = LDB(2), b3 = LDB(3), b4 = LDB(4), pb = LDB(5);
    float2 c0 = LDC(0), c1 = LDC(1), c2 = LDC(2), c3 = LDC(3), c4 = LDC(4), pc = LDC(5);

    if (tc < 3) {
        #pragma unroll
        for (int j = 0; j < 16; ++j) {
            step(re_full2(a0, a1, a3, a4), re_full2(b0, b1, b3, b4), re_full2(c0, c1, c3, c4), j);
            a0 = a1; a1 = a2; a2 = a3; a3 = a4; a4 = pa;
            b0 = b1; b1 = b2; b2 = b3; b3 = b4; b4 = pb;
            c0 = c1; c1 = c2; c2 = c3; c3 = c4; c4 = pc;
            if (j < 14) { pa = LDA(j + 6); pb = LDB(j + 6); pc = LDC(j + 6); }
        }
    } else {
        #pragma unroll
        for (int j = 0; j < 16; ++j) {
            float2 ra, rb, rc;
            if (j < 12) {
                ra = re_full2(a0, a1, a3, a4); rb = re_full2(b0, b1, b3, b4); rc = re_full2(c0, c1, c3, c4);
            } else if (j == 12) {
                ra.x = fmaf(3.f, a3.x - a0.x, a2.x - a1.x); ra.y = fmaf(3.f, a3.y - a0.y, a2.y - a1.y);
                rb.x = fmaf(3.f, b3.x - b0.x, b2.x - b1.x); rb.y = fmaf(3.f, b3.y - b0.y, b2.y - b1.y);
                rc.x = fmaf(3.f, c3.x - c0.x, c2.x - c1.x); rc.y = fmaf(3.f, c3.y - c0.y, c2.y - c1.y);
            } else if (j == 13) {
                ra.x = 2.f*(a2.x-a0.x); ra.y = 2.f*(a2.y-a0.y);
                rb.x = 2.f*(b2.x-b0.x); rb.y = 2.f*(b2.y-b0.y);
                rc.x = 2.f*(c2.x-c0.x); rc.y = 2.f*(c2.y-c0.y);
            } else if (j == 14) {
                ra.x = a1.x-a0.x; ra.y = a1.y-a0.y;
                rb.x = b1.x-b0.x; rb.y = b1.y-b0.y;
                rc.x = c1.x-c0.x; rc.y = c1.y-c0.y;
            } else {
                ra.x = ra.y = 0.f; rb = ra; rc = ra;
            }
            step(ra, rb, rc, j);
            a0 = a1; a1 = a2; a2 = a3; a3 = a4; a4 = pa;
            b0 = b1; b1 = b2; b2 = b3; b3 = b4; b4 = pb;
            c0 = c1; c1 = c2; c2 = c3; c3 = c4; c4 = pc;
            if (j < 10) { pa = LDA(j + 6); pb = LDB(j + 6); pc = LDC(j + 6); }
        }
    }
    #undef LDA
    #undef LDB
    #undef LDC

    const int lane = tid & 63;
    unsigned keep = 0x7BFF7BFFu;
    #pragma unroll
    for (int j = 0; j < 16; ++j) {
        unsigned a = acc[j];
        #pragma unroll
        for (int off = 32; off; off >>= 1)
            a = pk_min_f16(a, (unsigned)__shfl_xor((int)a, off, 64));
        if (lane == j) keep = a;
    }

    if (lane < 16) {
        union { unsigned u; _Float16 h[2]; } cv; cv.u = keep;
        const float amin = (float)cv.h[0];
        const float amax = -(float)cv.h[1];
        const float g0 = gelu_erf(amin), g1 = gelu_erf(amax);
        const float gmax = fmaxf(g0, g1);
        const float XSTAR = -0.7517916f;
        float gmin;
        if (amin >= XSTAR)      gmin = g0;
        else if (amax <= XSTAR) gmin = g1;
        else                    gmin = fminf(gelu_erf(XSTAR), fminf(g0, g1));
        atomicMin(&smin[lane], encf(gmin));
        atomicMax(&smax[lane], encf(gmax));
    }
    __syncthreads();
    if (tid < 16)            atomicMin(&gmm[t0 + tid], smin[tid]);
    else if (tid < 32)       atomicMax(&gmm[TT + t0 + tid - 16], smax[tid - 16]);
}

__global__ __launch_bounds__(256) void k_pass3(const unsigned* __restrict__ gs,
                                               const unsigned* __restrict__ gmm,
                                               float* __restrict__ out) {
    const int bid = blockIdx.x;
    const int b   = bid / 476;
    const int r   = bid - b * 476;
    const int t   = r / 7;
    const int seg = r - t * 7;
    const int base4 = seg * 1792 + threadIdx.x;
    float4* op = (float4*)out + ((size_t)b * 68 + t) * HW4 + base4;

    if (t < 4) {
        float4 z = make_float4(0.f, 0.f, 0.f, 0.f);
        #pragma unroll
        for (int k = 0; k < 7; ++k) op[k * 256] = z;
        return;
    }
    const int tm = t - 4;
    const float mn = decf(gmm[tm]);
    const float mx = decf(gmm[TT + tm]) - mn;
    const float inv = fast_rcp((mx != 0.f) ? mx : 1e-5f);
    const float A = inv, Bv = -mn * SUMW * inv;

    const uint2* gpp = (const uint2*)gs + ((size_t)b * TT + tm) * HW4 + base4;
    #pragma unroll
    for (int k = 0; k < 7; ++k) {
        uint2 v = gpp[k * 256];
        union { unsigned u; _Float16 h[2]; } lo, hi; lo.u = v.x; hi.u = v.y;
        float4 o;
        o.x = fmaf((float)lo.h[0], A, Bv);
        o.y = fmaf((float)lo.h[1], A, Bv);
        o.z = fmaf((float)hi.h[0], A, Bv);
        o.w = fmaf((float)hi.h[1], A, Bv);
        op[k * 256] = o;
    }
}

__global__ void k_consts(const unsigned* __restrict__ gmm, float* __restrict__ ab) {
    int t = threadIdx.x;
    float mn = decf(gmm[t]);
    float mx = decf(gmm[TT + t]) - mn;
    float inv = 1.0f / ((mx != 0.0f) ? mx : 1e-5f);
    ab[t]      = inv;
    ab[TT + t] = -mn * SUMW * inv;
}

__global__ __launch_bounds__(256) void k_pass2_direct(const float* __restrict__ x,
                                                      const float* __restrict__ ab,
                                                      float* __restrict__ out) {
    __shared__ float sA[TT], sB[TT];
    const int tid = threadIdx.x;
    if (tid < TT)          sA[tid] = ab[tid];
    else if (tid < 2 * TT) sB[tid - TT] = ab[tid];
    __syncthreads();

    const int pix = blockIdx.x * 256 + tid;
    const int b  = pix / HW;
    const int hw = pix - b * HW;
    const float* x0 = x + (size_t)(b * 3) * (TT * (size_t)HW) + hw;
    const float* x1 = x0 + (size_t)TT * HW;
    const float* x2 = x1 + (size_t)TT * HW;
    float* op = out + (size_t)b * (68 * (size_t)HW) + hw;

    op[0] = 0.f; op[HW] = 0.f; op[2 * (size_t)HW] = 0.f; op[3 * (size_t)HW] = 0.f;
    op += 4 * (size_t)HW;

    float a0 = x0[0], a1 = x0[HW], a2 = x0[2*HW], a3 = x0[3*HW], a4 = x0[4*HW];
    float b0 = x1[0], b1 = x1[HW], b2 = x1[2*HW], b3 = x1[3*HW], b4 = x1[4*HW];
    float c0 = x2[0], c1 = x2[HW], c2 = x2[2*HW], c3 = x2[3*HW], c4 = x2[4*HW];

    auto emit = [&](int t, float ra, float rb, float rc) {
        float gsv = 0.2989f * gelu_erf(ra) + 0.587f * gelu_erf(rb) + 0.114f * gelu_erf(rc);
        op[(size_t)t * HW] = fmaf(gsv, sA[t], sB[t]);
    };

    for (int t = 0; t < 59; ++t) {
        emit(t, 4.f*(a4-a0) + 2.f*(a3-a1), 4.f*(b4-b0) + 2.f*(b3-b1), 4.f*(c4-c0) + 2.f*(c3-c1));
        a0=a1; a1=a2; a2=a3; a3=a4; a4 = x0[(size_t)(t+5)*HW];
        b0=b1; b1=b2; b2=b3; b3=b4; b4 = x1[(size_t)(t+5)*HW];
        c0=c1; c1=c2; c2=c3; c3=c4; c4 = x2[(size_t)(t+5)*HW];
    }
    emit(59, 4.f*(a4-a0) + 2.f*(a3-a1), 4.f*(b4-b0) + 2.f*(b3-b1), 4.f*(c4-c0) + 2.f*(c3-c1));
    a0=a1; a1=a2; a2=a3; a3=a4; b0=b1; b1=b2; b2=b3; b3=b4; c0=c1; c1=c2; c2=c3; c3=c4;
    emit(60, 3.f*(a3-a0) + (a2-a1), 3.f*(b3-b0) + (b2-b1), 3.f*(c3-c0) + (c2-c1));
    a0=a1; a1=a2; a2=a3; b0=b1; b1=b2; b2=b3; c0=c1; c1=c2; c2=c3;
    emit(61, 2.f*(a2-a0), 2.f*(b2-b0), 2.f*(c2-c0));
    a0=a1; a1=a2; b0=b1; b1=b2; c0=c1; c1=c2;
    emit(62, a1-a0, b1-b0, c1-c0);
    op[63 * (size_t)HW] = sB[63];
}

extern "C" void kernel_launch(void* const* d_in, const int* in_sizes, int n_in,
                              void* d_out, int out_size, void* d_ws, size_t ws_size,
                              hipStream_t stream) {
    const float* x = (const float*)d_in[0];
    float* out = (float*)d_out;
    unsigned* gmm = (unsigned*)d_ws;                       // 128 u32
    float* ab = (float*)d_ws + 128;                        // 128 f32 (fallback only)
    unsigned* gs = (unsigned*)((char*)d_ws + 1024);
    const size_t need = 1024 + (size_t)8 * TT * (size_t)HW * 2;   // ~51.4 MB

    // init gmm: 0xFF.. == encoded +inf (min half), 0x00.. < all encodings (max half)
    hipMemsetAsync(gmm, 0xFF, TT * sizeof(unsigned), stream);
    hipMemsetAsync(gmm + TT, 0x00, TT * sizeof(unsigned), stream);

    // cooperative path: requires all 1568 blocks co-resident (host-side queries
    // are not stream ops -> graph-capture-safe, deterministic)
    bool coop_done = false;
    int dev = 0;
    (void)hipGetDevice(&dev);
    int ncu = 0;
    (void)hipDeviceGetAttribute(&ncu, hipDeviceAttributeMultiprocessorCount, dev);
    int maxb = 0;
    (void)hipOccupancyMaxActiveBlocksPerMultiprocessor(&maxb, k_fused, 256, 0);
    if ((long long)maxb * (long long)ncu >= 1568LL) {
        void* args[] = { (void*)&x, (void*)&gmm, (void*)&out };
        hipError_t e = hipLaunchCooperativeKernel((void*)k_fused, dim3(1568), dim3(256),
                                                  args, 0, stream);
        if (e == hipSuccess) coop_done = true;
        else (void)hipGetLastError();   // clear, fall through to fallback
    }

    if (!coop_done) {
        if (ws_size >= need) {
            k_pass1<true><<<3136, 256, 0, stream>>>(x, gmm, gs);
            k_pass3<<<3808, 256, 0, stream>>>(gs, gmm, out);
        } else {
            k_pass1<false><<<3136, 256, 0, stream>>>(x, gmm, nullptr);
            k_consts<<<1, 64, 0, stream>>>(gmm, ab);
            k_pass2_direct<<<1568, 256, 0, stream>>>(x, ab, out);
        }
    }
}

// Round 10
// 131.967 us; speedup vs baseline: 1.0469x; 1.0044x over previous
//
#include <hip/hip_runtime.h>

#define HW 50176            // 224*224
#define HW2 25088           // HW/2 (u32 = 2 f16 per frame)
#define HW4 12544           // HW/4
#define TT 64
#define SUMW 0.9999f        // 0.2989+0.587+0.114

__device__ __forceinline__ float gelu_erf(float x) {
    return 0.5f * x * (1.0f + erff(0.70710678f * x));
}
__device__ __forceinline__ float fast_rcp(float v) {
    float r; asm("v_rcp_f32 %0, %1" : "=v"(r) : "v"(v)); return r;
}
__device__ __forceinline__ float gelu_fast(float x) {
    // tanh-form gelu; max |err| ~3e-3 vs erf (cancels through normalize)
    float x2 = x * x;
    float e = exp2f(-x * fmaf(0.1029433f, x2, 2.3022078f));
    return x * fast_rcp(1.0f + e);
}
__device__ __forceinline__ unsigned encf(float f) {
    unsigned u = __float_as_uint(f);
    return (u & 0x80000000u) ? ~u : (u | 0x80000000u);
}
__device__ __forceinline__ float decf(unsigned u) {
    unsigned b = (u & 0x80000000u) ? (u ^ 0x80000000u) : ~u;
    return __uint_as_float(b);
}
__device__ __forceinline__ unsigned pk_min_f16(unsigned a, unsigned b) {
    unsigned r; asm("v_pk_min_f16 %0, %1, %2" : "=v"(r) : "v"(a), "v"(b)); return r;
}
__device__ __forceinline__ unsigned pack2(float lo, float hi) {
    auto p = __builtin_amdgcn_cvt_pkrtz(lo, hi);
    return __builtin_bit_cast(unsigned, p);
}
__device__ __forceinline__ unsigned pk2(float r) { return pack2(r, -r); }   // (r,-r)
__device__ __forceinline__ unsigned mm2(float2 r) { return pk_min_f16(pk2(r.x), pk2(r.y)); }

// Pass 1 (fused, COMPACT CODE): 2 px/thread, ALL 64 windows per thread (amp=1.0).
// Runtime outer loop over 7 groups of 8 full-weight windows (inner unroll 8 keeps
// acc[8] register-indexed), peeled final group for tail weights. Flush per group.
// Writes gs = sum_c w_c*gelu(re_c) as packed 2xf16.
template<bool WGS>
__global__ __launch_bounds__(256, 4) void k_pass1(const float* __restrict__ x,
                                                  unsigned* __restrict__ gmm,
                                                  unsigned* __restrict__ gs) {
    __shared__ unsigned smin[TT], smax[TT];
    const int tid = threadIdx.x;
    if (tid < TT) smin[tid] = 0xFFFFFFFFu;
    else if (tid < 2 * TT) smax[tid - TT] = 0u;
    __syncthreads();

    const int bid = blockIdx.x;            // < 784 = 8 b × 98 hwb
    const int b   = bid / 98;
    const int hwb = bid - b * 98;
    const int hw  = (hwb * 256 + tid) * 2;
    const float* xa = x + ((size_t)(b * 3 + 0) * TT) * (size_t)HW + hw;
    const float* xb = x + ((size_t)(b * 3 + 1) * TT) * (size_t)HW + hw;
    const float* xc = x + ((size_t)(b * 3 + 2) * TT) * (size_t)HW + hw;
    unsigned* gp = gs + ((size_t)b * TT) * (size_t)HW2 + (hwb * 256 + tid);

    const int lane = tid & 63;
    unsigned keep = 0x7BFF7BFFu;           // lane L ends up holding window t=L

    // window: frames t..t+4 in a0..a4, 1-deep prefetch pa = t+5; pointers -> t+6
    float2 a0 = *(const float2*)xa, b0 = *(const float2*)xb, c0 = *(const float2*)xc;
    float2 a1 = *(const float2*)(xa + HW), b1 = *(const float2*)(xb + HW), c1 = *(const float2*)(xc + HW);
    float2 a2 = *(const float2*)(xa + 2*(size_t)HW), b2 = *(const float2*)(xb + 2*(size_t)HW), c2 = *(const float2*)(xc + 2*(size_t)HW);
    float2 a3 = *(const float2*)(xa + 3*(size_t)HW), b3 = *(const float2*)(xb + 3*(size_t)HW), c3 = *(const float2*)(xc + 3*(size_t)HW);
    float2 a4 = *(const float2*)(xa + 4*(size_t)HW), b4 = *(const float2*)(xb + 4*(size_t)HW), c4 = *(const float2*)(xc + 4*(size_t)HW);
    float2 pa = *(const float2*)(xa + 5*(size_t)HW), pb = *(const float2*)(xb + 5*(size_t)HW), pc = *(const float2*)(xc + 5*(size_t)HW);
    xa += 6 * (size_t)HW; xb += 6 * (size_t)HW; xc += 6 * (size_t)HW;

    unsigned acc[8];

    // full-weight step (weights -4,-2,0,2,4) + shift + unconditional prefetch
    #define STEP_FULL(J) { \
        float2 ra, rb, rc; \
        ra.x = fmaf(4.f, a4.x - a0.x, 2.f * (a3.x - a1.x)); ra.y = fmaf(4.f, a4.y - a0.y, 2.f * (a3.y - a1.y)); \
        rb.x = fmaf(4.f, b4.x - b0.x, 2.f * (b3.x - b1.x)); rb.y = fmaf(4.f, b4.y - b0.y, 2.f * (b3.y - b1.y)); \
        rc.x = fmaf(4.f, c4.x - c0.x, 2.f * (c3.x - c1.x)); rc.y = fmaf(4.f, c4.y - c0.y, 2.f * (c3.y - c1.y)); \
        acc[J] = pk_min_f16(acc[J], pk_min_f16(pk_min_f16(mm2(ra), mm2(rb)), mm2(rc))); \
        if constexpr (WGS) { \
            float gx = fmaf(0.114f, gelu_fast(rc.x), fmaf(0.587f, gelu_fast(rb.x), 0.2989f * gelu_fast(ra.x))); \
            float gy = fmaf(0.114f, gelu_fast(rc.y), fmaf(0.587f, gelu_fast(rb.y), 0.2989f * gelu_fast(ra.y))); \
            *gp = pack2(gx, gy); \
        } \
        gp += HW2; \
        a0 = a1; a1 = a2; a2 = a3; a3 = a4; a4 = pa; \
        b0 = b1; b1 = b2; b2 = b3; b3 = b4; b4 = pb; \
        c0 = c1; c1 = c2; c2 = c3; c3 = c4; c4 = pc; }

    #define PREFETCH() { pa = *(const float2*)xa; pb = *(const float2*)xb; pc = *(const float2*)xc; \
                         xa += HW; xb += HW; xc += HW; }

    // butterfly-reduce one acc; lane T keeps it
    #define FLUSH(J, T) { unsigned v = acc[J]; \
        v = pk_min_f16(v, (unsigned)__shfl_xor((int)v, 32, 64)); \
        v = pk_min_f16(v, (unsigned)__shfl_xor((int)v, 16, 64)); \
        v = pk_min_f16(v, (unsigned)__shfl_xor((int)v,  8, 64)); \
        v = pk_min_f16(v, (unsigned)__shfl_xor((int)v,  4, 64)); \
        v = pk_min_f16(v, (unsigned)__shfl_xor((int)v,  2, 64)); \
        v = pk_min_f16(v, (unsigned)__shfl_xor((int)v,  1, 64)); \
        if (lane == (T)) keep = v; }

    // ---- runtime loop: groups g=0..6 cover t=0..55, all full-weight ----
    for (int g = 0; g < 7; ++g) {
        #pragma unroll
        for (int j = 0; j < 8; ++j) acc[j] = 0x7BFF7BFFu;
        #pragma unroll
        for (int j = 0; j < 8; ++j) {
            STEP_FULL(j)
            PREFETCH()                      // frame t+6 <= 61, always valid
        }
        #pragma unroll
        for (int j = 0; j < 8; ++j) FLUSH(j, g * 8 + j)
    }

    // ---- peeled final group: t=56..63 (entry: a0..a4 = 56..60, pa = 61, ptr -> 62)
    {
        #pragma unroll
        for (int j = 0; j < 8; ++j) acc[j] = 0x7BFF7BFFu;
        STEP_FULL(0) PREFETCH()             // t=56, load 62
        STEP_FULL(1) PREFETCH()             // t=57, load 63
        STEP_FULL(2)                        // t=58
        STEP_FULL(3)                        // t=59 -> a0..a3 = 60..63
        {   // t=60: weights -3,-1,1,3
            float2 ra, rb, rc;
            ra.x = fmaf(3.f, a3.x - a0.x, a2.x - a1.x); ra.y = fmaf(3.f, a3.y - a0.y, a2.y - a1.y);
            rb.x = fmaf(3.f, b3.x - b0.x, b2.x - b1.x); rb.y = fmaf(3.f, b3.y - b0.y, b2.y - b1.y);
            rc.x = fmaf(3.f, c3.x - c0.x, c2.x - c1.x); rc.y = fmaf(3.f, c3.y - c0.y, c2.y - c1.y);
            acc[4] = pk_min_f16(acc[4], pk_min_f16(pk_min_f16(mm2(ra), mm2(rb)), mm2(rc)));
            if constexpr (WGS) {
                float gx = fmaf(0.114f, gelu_fast(rc.x), fmaf(0.587f, gelu_fast(rb.x), 0.2989f * gelu_fast(ra.x)));
                float gy = fmaf(0.114f, gelu_fast(rc.y), fmaf(0.587f, gelu_fast(rb.y), 0.2989f * gelu_fast(ra.y)));
                *gp = pack2(gx, gy);
            }
            gp += HW2;
            a0 = a1; a1 = a2; a2 = a3;
            b0 = b1; b1 = b2; b2 = b3;
            c0 = c1; c1 = c2; c2 = c3;
        }
        {   // t=61: weights -2,0,2
            float2 ra, rb, rc;
            ra.x = 2.f*(a2.x-a0.x); ra.y = 2.f*(a2.y-a0.y);
            rb.x = 2.f*(b2.x-b0.x); rb.y = 2.f*(b2.y-b0.y);
            rc.x = 2.f*(c2.x-c0.x); rc.y = 2.f*(c2.y-c0.y);
            acc[5] = pk_min_f16(acc[5], pk_min_f16(pk_min_f16(mm2(ra), mm2(rb)), mm2(rc)));
            if constexpr (WGS) {
                float gx = fmaf(0.114f, gelu_fast(rc.x), fmaf(0.587f, gelu_fast(rb.x), 0.2989f * gelu_fast(ra.x)));
                float gy = fmaf(0.114f, gelu_fast(rc.y), fmaf(0.587f, gelu_fast(rb.y), 0.2989f * gelu_fast(ra.y)));
                *gp = pack2(gx, gy);
            }
            gp += HW2;
            a0 = a1; a1 = a2;
            b0 = b1; b1 = b2;
            c0 = c1; c1 = c2;
        }
        {   // t=62: weights -1,1
            float2 ra, rb, rc;
            ra.x = a1.x-a0.x; ra.y = a1.y-a0.y;
            rb.x = b1.x-b0.x; rb.y = b1.y-b0.y;
            rc.x = c1.x-c0.x; rc.y = c1.y-c0.y;
            acc[6] = pk_min_f16(acc[6], pk_min_f16(pk_min_f16(mm2(ra), mm2(rb)), mm2(rc)));
            if constexpr (WGS) {
                float gx = fmaf(0.114f, gelu_fast(rc.x), fmaf(0.587f, gelu_fast(rb.x), 0.2989f * gelu_fast(ra.x)));
                float gy = fmaf(0.114f, gelu_fast(rc.y), fmaf(0.587f, gelu_fast(rb.y), 0.2989f * gelu_fast(ra.y)));
                *gp = pack2(gx, gy);
            }
            gp += HW2;
        }
        {   // t=63: weight 0 -> re = 0, gs = 0
            acc[7] = pk_min_f16(acc[7], 0u);       // pk2(0) == 0
            if constexpr (WGS) *gp = 0u;
        }
        #pragma unroll
        for (int j = 0; j < 8; ++j) FLUSH(j, 56 + j)
    }
    #undef STEP_FULL
    #undef PREFETCH
    #undef FLUSH

    // lane L holds window t=L: tail gelu eval + LDS/global reduce
    {
        union { unsigned u; _Float16 h[2]; } cv; cv.u = keep;
        const float amin = (float)cv.h[0];
        const float amax = -(float)cv.h[1];
        const float g0 = gelu_erf(amin), g1 = gelu_erf(amax);
        const float gmax = fmaxf(g0, g1);
        const float XSTAR = -0.7517916f;           // argmin of gelu
        float gmin;
        if (amin >= XSTAR)      gmin = g0;
        else if (amax <= XSTAR) gmin = g1;
        else                    gmin = fminf(gelu_erf(XSTAR), fminf(g0, g1));
        atomicMin(&smin[lane], encf(gmin));
        atomicMax(&smax[lane], encf(gmax));
    }
    __syncthreads();
    if (tid < TT)            atomicMin(&gmm[tid], smin[tid]);
    else if (tid < 2 * TT)   atomicMax(&gmm[TT + tid - TT], smax[tid - TT]);
}

// Pass 3: out[b,t] = (t<4) ? 0 : gs[b,t-4]*A + B, A/B derived from gmm inline.
__global__ __launch_bounds__(256) void k_pass3(const unsigned* __restrict__ gs,
                                               const unsigned* __restrict__ gmm,
                                               float* __restrict__ out) {
    const int bid = blockIdx.x;
    const int b   = bid / 476;             // 476 = 68*7
    const int r   = bid - b * 476;
    const int t   = r / 7;
    const int seg = r - t * 7;
    const int base4 = seg * 1792 + threadIdx.x;
    float4* op = (float4*)out + ((size_t)b * 68 + t) * HW4 + base4;

    if (t < 4) {
        float4 z = make_float4(0.f, 0.f, 0.f, 0.f);
        #pragma unroll
        for (int k = 0; k < 7; ++k) op[k * 256] = z;
        return;
    }
    const int tm = t - 4;
    const float mn = decf(gmm[tm]);
    const float mx = decf(gmm[TT + tm]) - mn;
    const float inv = fast_rcp((mx != 0.f) ? mx : 1e-5f);
    const float A = inv, Bv = -mn * SUMW * inv;

    const uint2* gpp = (const uint2*)gs + ((size_t)b * TT + tm) * HW4 + base4;
    #pragma unroll
    for (int k = 0; k < 7; ++k) {
        uint2 v = gpp[k * 256];
        union { unsigned u; _Float16 h[2]; } lo, hi; lo.u = v.x; hi.u = v.y;
        float4 o;
        o.x = fmaf((float)lo.h[0], A, Bv);
        o.y = fmaf((float)lo.h[1], A, Bv);
        o.z = fmaf((float)hi.h[0], A, Bv);
        o.w = fmaf((float)hi.h[1], A, Bv);
        op[k * 256] = o;
    }
}

// Fallback helpers (ws too small for gs): consts kernel + direct erf pass
__global__ void k_consts(const unsigned* __restrict__ gmm, float* __restrict__ ab) {
    int t = threadIdx.x;
    float mn = decf(gmm[t]);
    float mx = decf(gmm[TT + t]) - mn;
    float inv = 1.0f / ((mx != 0.0f) ? mx : 1e-5f);
    ab[t]      = inv;
    ab[TT + t] = -mn * SUMW * inv;
}

__global__ __launch_bounds__(256) void k_pass2_direct(const float* __restrict__ x,
                                                      const float* __restrict__ ab,
                                                      float* __restrict__ out) {
    __shared__ float sA[TT], sB[TT];
    const int tid = threadIdx.x;
    if (tid < TT)          sA[tid] = ab[tid];
    else if (tid < 2 * TT) sB[tid - TT] = ab[tid];
    __syncthreads();

    const int pix = blockIdx.x * 256 + tid;
    const int b  = pix / HW;
    const int hw = pix - b * HW;
    const float* x0 = x + (size_t)(b * 3) * (TT * (size_t)HW) + hw;
    const float* x1 = x0 + (size_t)TT * HW;
    const float* x2 = x1 + (size_t)TT * HW;
    float* op = out + (size_t)b * (68 * (size_t)HW) + hw;

    op[0] = 0.f; op[HW] = 0.f; op[2 * (size_t)HW] = 0.f; op[3 * (size_t)HW] = 0.f;
    op += 4 * (size_t)HW;

    float a0 = x0[0], a1 = x0[HW], a2 = x0[2*HW], a3 = x0[3*HW], a4 = x0[4*HW];
    float b0 = x1[0], b1 = x1[HW], b2 = x1[2*HW], b3 = x1[3*HW], b4 = x1[4*HW];
    float c0 = x2[0], c1 = x2[HW], c2 = x2[2*HW], c3 = x2[3*HW], c4 = x2[4*HW];

    auto emit = [&](int t, float ra, float rb, float rc) {
        float gsv = 0.2989f * gelu_erf(ra) + 0.587f * gelu_erf(rb) + 0.114f * gelu_erf(rc);
        op[(size_t)t * HW] = fmaf(gsv, sA[t], sB[t]);
    };

    for (int t = 0; t < 59; ++t) {
        emit(t, 4.f*(a4-a0) + 2.f*(a3-a1), 4.f*(b4-b0) + 2.f*(b3-b1), 4.f*(c4-c0) + 2.f*(c3-c1));
        a0=a1; a1=a2; a2=a3; a3=a4; a4 = x0[(size_t)(t+5)*HW];
        b0=b1; b1=b2; b2=b3; b3=b4; b4 = x1[(size_t)(t+5)*HW];
        c0=c1; c1=c2; c2=c3; c3=c4; c4 = x2[(size_t)(t+5)*HW];
    }
    emit(59, 4.f*(a4-a0) + 2.f*(a3-a1), 4.f*(b4-b0) + 2.f*(b3-b1), 4.f*(c4-c0) + 2.f*(c3-c1));
    a0=a1; a1=a2; a2=a3; a3=a4; b0=b1; b1=b2; b2=b3; b3=b4; c0=c1; c1=c2; c2=c3; c3=c4;
    emit(60, 3.f*(a3-a0) + (a2-a1), 3.f*(b3-b0) + (b2-b1), 3.f*(c3-c0) + (c2-c1));
    a0=a1; a1=a2; a2=a3; b0=b1; b1=b2; b2=b3; c0=c1; c1=c2; c2=c3;
    emit(61, 2.f*(a2-a0), 2.f*(b2-b0), 2.f*(c2-c0));
    a0=a1; a1=a2; b0=b1; b1=b2; c0=c1; c1=c2;
    emit(62, a1-a0, b1-b0, c1-c0);
    op[63 * (size_t)HW] = sB[63];
}

extern "C" void kernel_launch(void* const* d_in, const int* in_sizes, int n_in,
                              void* d_out, int out_size, void* d_ws, size_t ws_size,
                              hipStream_t stream) {
    const float* x = (const float*)d_in[0];
    float* out = (float*)d_out;
    unsigned* gmm = (unsigned*)d_ws;                       // 128 u32
    float* ab = (float*)d_ws + 128;                        // 128 f32 (fallback only)
    unsigned* gs = (unsigned*)((char*)d_ws + 1024);
    const size_t need = 1024 + (size_t)8 * TT * (size_t)HW * 2;   // ~51.4 MB

    // init gmm: 0xFF.. == encoded +inf (min half), 0x00.. < all encodings (max half)
    hipMemsetAsync(gmm, 0xFF, TT * sizeof(unsigned), stream);
    hipMemsetAsync(gmm + TT, 0x00, TT * sizeof(unsigned), stream);

    if (ws_size >= need) {
        k_pass1<true><<<784, 256, 0, stream>>>(x, gmm, gs);
        k_pass3<<<3808, 256, 0, stream>>>(gs, gmm, out);
    } else {
        k_pass1<false><<<784, 256, 0, stream>>>(x, gmm, nullptr);
        k_consts<<<1, 64, 0, stream>>>(gmm, ab);
        k_pass2_direct<<<1568, 256, 0, stream>>>(x, ab, out);
    }
}

// Round 11
// 124.368 us; speedup vs baseline: 1.1109x; 1.0611x over previous
//
#include <hip/hip_runtime.h>

#define HW 50176            // 224*224
#define HW2 25088           // HW/2 (u32 = 2 f16 per frame)
#define HW4 12544           // HW/4
#define TT 64
#define NBP 784             // pass1 grid: 8 b × 98 hwb, 2 px/thread
#define SUMW 0.9999f        // 0.2989+0.587+0.114

__device__ __forceinline__ float gelu_erf(float x) {
    return 0.5f * x * (1.0f + erff(0.70710678f * x));
}
__device__ __forceinline__ float fast_rcp(float v) {
    float r; asm("v_rcp_f32 %0, %1" : "=v"(r) : "v"(v)); return r;
}
__device__ __forceinline__ float gelu_fast(float x) {
    // tanh-form gelu; max |err| ~3e-3 vs erf (cancels through normalize)
    float x2 = x * x;
    float e = exp2f(-x * fmaf(0.1029433f, x2, 2.3022078f));
    return x * fast_rcp(1.0f + e);
}
__device__ __forceinline__ unsigned encf(float f) {
    unsigned u = __float_as_uint(f);
    return (u & 0x80000000u) ? ~u : (u | 0x80000000u);
}
__device__ __forceinline__ float decf(unsigned u) {
    unsigned b = (u & 0x80000000u) ? (u ^ 0x80000000u) : ~u;
    return __uint_as_float(b);
}
__device__ __forceinline__ unsigned pk_min_f16(unsigned a, unsigned b) {
    unsigned r; asm("v_pk_min_f16 %0, %1, %2" : "=v"(r) : "v"(a), "v"(b)); return r;
}
__device__ __forceinline__ unsigned pack2(float lo, float hi) {
    auto p = __builtin_amdgcn_cvt_pkrtz(lo, hi);
    return __builtin_bit_cast(unsigned, p);
}
__device__ __forceinline__ unsigned pk2(float r) { return pack2(r, -r); }   // (r,-r)
__device__ __forceinline__ unsigned mm2(float2 r) { return pk_min_f16(pk2(r.x), pk2(r.y)); }

// Pass 1: identical to round 10 EXCEPT the epilogue — per-block partial stores
// (part[row][bid]) replace the 128 contended device-scope global atomics.
template<bool WGS>
__global__ __launch_bounds__(256, 4) void k_pass1(const float* __restrict__ x,
                                                  unsigned* __restrict__ part,
                                                  unsigned* __restrict__ gs) {
    __shared__ unsigned smin[TT], smax[TT];
    const int tid = threadIdx.x;
    if (tid < TT) smin[tid] = 0xFFFFFFFFu;
    else if (tid < 2 * TT) smax[tid - TT] = 0u;
    __syncthreads();

    const int bid = blockIdx.x;            // < 784 = 8 b × 98 hwb
    const int b   = bid / 98;
    const int hwb = bid - b * 98;
    const int hw  = (hwb * 256 + tid) * 2;
    const float* xa = x + ((size_t)(b * 3 + 0) * TT) * (size_t)HW + hw;
    const float* xb = x + ((size_t)(b * 3 + 1) * TT) * (size_t)HW + hw;
    const float* xc = x + ((size_t)(b * 3 + 2) * TT) * (size_t)HW + hw;
    unsigned* gp = gs + ((size_t)b * TT) * (size_t)HW2 + (hwb * 256 + tid);

    const int lane = tid & 63;
    unsigned keep = 0x7BFF7BFFu;           // lane L ends up holding window t=L

    float2 a0 = *(const float2*)xa, b0 = *(const float2*)xb, c0 = *(const float2*)xc;
    float2 a1 = *(const float2*)(xa + HW), b1 = *(const float2*)(xb + HW), c1 = *(const float2*)(xc + HW);
    float2 a2 = *(const float2*)(xa + 2*(size_t)HW), b2 = *(const float2*)(xb + 2*(size_t)HW), c2 = *(const float2*)(xc + 2*(size_t)HW);
    float2 a3 = *(const float2*)(xa + 3*(size_t)HW), b3 = *(const float2*)(xb + 3*(size_t)HW), c3 = *(const float2*)(xc + 3*(size_t)HW);
    float2 a4 = *(const float2*)(xa + 4*(size_t)HW), b4 = *(const float2*)(xb + 4*(size_t)HW), c4 = *(const float2*)(xc + 4*(size_t)HW);
    float2 pa = *(const float2*)(xa + 5*(size_t)HW), pb = *(const float2*)(xb + 5*(size_t)HW), pc = *(const float2*)(xc + 5*(size_t)HW);
    xa += 6 * (size_t)HW; xb += 6 * (size_t)HW; xc += 6 * (size_t)HW;

    unsigned acc[8];

    #define STEP_FULL(J) { \
        float2 ra, rb, rc; \
        ra.x = fmaf(4.f, a4.x - a0.x, 2.f * (a3.x - a1.x)); ra.y = fmaf(4.f, a4.y - a0.y, 2.f * (a3.y - a1.y)); \
        rb.x = fmaf(4.f, b4.x - b0.x, 2.f * (b3.x - b1.x)); rb.y = fmaf(4.f, b4.y - b0.y, 2.f * (b3.y - b1.y)); \
        rc.x = fmaf(4.f, c4.x - c0.x, 2.f * (c3.x - c1.x)); rc.y = fmaf(4.f, c4.y - c0.y, 2.f * (c3.y - c1.y)); \
        acc[J] = pk_min_f16(acc[J], pk_min_f16(pk_min_f16(mm2(ra), mm2(rb)), mm2(rc))); \
        if constexpr (WGS) { \
            float gx = fmaf(0.114f, gelu_fast(rc.x), fmaf(0.587f, gelu_fast(rb.x), 0.2989f * gelu_fast(ra.x))); \
            float gy = fmaf(0.114f, gelu_fast(rc.y), fmaf(0.587f, gelu_fast(rb.y), 0.2989f * gelu_fast(ra.y))); \
            *gp = pack2(gx, gy); \
        } \
        gp += HW2; \
        a0 = a1; a1 = a2; a2 = a3; a3 = a4; a4 = pa; \
        b0 = b1; b1 = b2; b2 = b3; b3 = b4; b4 = pb; \
        c0 = c1; c1 = c2; c2 = c3; c3 = c4; c4 = pc; }

    #define PREFETCH() { pa = *(const float2*)xa; pb = *(const float2*)xb; pc = *(const float2*)xc; \
                         xa += HW; xb += HW; xc += HW; }

    #define FLUSH(J, T) { unsigned v = acc[J]; \
        v = pk_min_f16(v, (unsigned)__shfl_xor((int)v, 32, 64)); \
        v = pk_min_f16(v, (unsigned)__shfl_xor((int)v, 16, 64)); \
        v = pk_min_f16(v, (unsigned)__shfl_xor((int)v,  8, 64)); \
        v = pk_min_f16(v, (unsigned)__shfl_xor((int)v,  4, 64)); \
        v = pk_min_f16(v, (unsigned)__shfl_xor((int)v,  2, 64)); \
        v = pk_min_f16(v, (unsigned)__shfl_xor((int)v,  1, 64)); \
        if (lane == (T)) keep = v; }

    for (int g = 0; g < 7; ++g) {
        #pragma unroll
        for (int j = 0; j < 8; ++j) acc[j] = 0x7BFF7BFFu;
        #pragma unroll
        for (int j = 0; j < 8; ++j) {
            STEP_FULL(j)
            PREFETCH()
        }
        #pragma unroll
        for (int j = 0; j < 8; ++j) FLUSH(j, g * 8 + j)
    }

    {   // peeled final group: t=56..63
        #pragma unroll
        for (int j = 0; j < 8; ++j) acc[j] = 0x7BFF7BFFu;
        STEP_FULL(0) PREFETCH()             // t=56, load 62
        STEP_FULL(1) PREFETCH()             // t=57, load 63
        STEP_FULL(2)                        // t=58
        STEP_FULL(3)                        // t=59 -> a0..a3 = 60..63
        {   // t=60: weights -3,-1,1,3
            float2 ra, rb, rc;
            ra.x = fmaf(3.f, a3.x - a0.x, a2.x - a1.x); ra.y = fmaf(3.f, a3.y - a0.y, a2.y - a1.y);
            rb.x = fmaf(3.f, b3.x - b0.x, b2.x - b1.x); rb.y = fmaf(3.f, b3.y - b0.y, b2.y - b1.y);
            rc.x = fmaf(3.f, c3.x - c0.x, c2.x - c1.x); rc.y = fmaf(3.f, c3.y - c0.y, c2.y - c1.y);
            acc[4] = pk_min_f16(acc[4], pk_min_f16(pk_min_f16(mm2(ra), mm2(rb)), mm2(rc)));
            if constexpr (WGS) {
                float gx = fmaf(0.114f, gelu_fast(rc.x), fmaf(0.587f, gelu_fast(rb.x), 0.2989f * gelu_fast(ra.x)));
                float gy = fmaf(0.114f, gelu_fast(rc.y), fmaf(0.587f, gelu_fast(rb.y), 0.2989f * gelu_fast(ra.y)));
                *gp = pack2(gx, gy);
            }
            gp += HW2;
            a0 = a1; a1 = a2; a2 = a3;
            b0 = b1; b1 = b2; b2 = b3;
            c0 = c1; c1 = c2; c2 = c3;
        }
        {   // t=61: weights -2,0,2
            float2 ra, rb, rc;
            ra.x = 2.f*(a2.x-a0.x); ra.y = 2.f*(a2.y-a0.y);
            rb.x = 2.f*(b2.x-b0.x); rb.y = 2.f*(b2.y-b0.y);
            rc.x = 2.f*(c2.x-c0.x); rc.y = 2.f*(c2.y-c0.y);
            acc[5] = pk_min_f16(acc[5], pk_min_f16(pk_min_f16(mm2(ra), mm2(rb)), mm2(rc)));
            if constexpr (WGS) {
                float gx = fmaf(0.114f, gelu_fast(rc.x), fmaf(0.587f, gelu_fast(rb.x), 0.2989f * gelu_fast(ra.x)));
                float gy = fmaf(0.114f, gelu_fast(rc.y), fmaf(0.587f, gelu_fast(rb.y), 0.2989f * gelu_fast(ra.y)));
                *gp = pack2(gx, gy);
            }
            gp += HW2;
            a0 = a1; a1 = a2;
            b0 = b1; b1 = b2;
            c0 = c1; c1 = c2;
        }
        {   // t=62: weights -1,1
            float2 ra, rb, rc;
            ra.x = a1.x-a0.x; ra.y = a1.y-a0.y;
            rb.x = b1.x-b0.x; rb.y = b1.y-b0.y;
            rc.x = c1.x-c0.x; rc.y = c1.y-c0.y;
            acc[6] = pk_min_f16(acc[6], pk_min_f16(pk_min_f16(mm2(ra), mm2(rb)), mm2(rc)));
            if constexpr (WGS) {
                float gx = fmaf(0.114f, gelu_fast(rc.x), fmaf(0.587f, gelu_fast(rb.x), 0.2989f * gelu_fast(ra.x)));
                float gy = fmaf(0.114f, gelu_fast(rc.y), fmaf(0.587f, gelu_fast(rb.y), 0.2989f * gelu_fast(ra.y)));
                *gp = pack2(gx, gy);
            }
            gp += HW2;
        }
        {   // t=63: weight 0 -> re = 0, gs = 0
            acc[7] = pk_min_f16(acc[7], 0u);
            if constexpr (WGS) *gp = 0u;
        }
        #pragma unroll
        for (int j = 0; j < 8; ++j) FLUSH(j, 56 + j)
    }
    #undef STEP_FULL
    #undef PREFETCH
    #undef FLUSH

    {   // lane L holds window t=L: tail gelu eval + LDS reduce
        union { unsigned u; _Float16 h[2]; } cv; cv.u = keep;
        const float amin = (float)cv.h[0];
        const float amax = -(float)cv.h[1];
        const float g0 = gelu_erf(amin), g1 = gelu_erf(amax);
        const float gmax = fmaxf(g0, g1);
        const float XSTAR = -0.7517916f;
        float gmin;
        if (amin >= XSTAR)      gmin = g0;
        else if (amax <= XSTAR) gmin = g1;
        else                    gmin = fminf(gelu_erf(XSTAR), fminf(g0, g1));
        atomicMin(&smin[lane], encf(gmin));
        atomicMax(&smax[lane], encf(gmax));
    }
    __syncthreads();
    // per-block partial store (transposed: row-major over t, column = bid)
    if (tid < TT)            part[(size_t)tid * NBP + bid] = smin[tid];
    else if (tid < 2 * TT)   part[(size_t)tid * NBP + bid] = smax[tid - TT];
}

// block-wide reduce of partial rows tm (min) and 64+tm (max); returns via refs
__device__ __forceinline__ void reduce_part(const unsigned* __restrict__ part, int tm,
                                            int tid, float& A, float& Bv) {
    __shared__ unsigned rm[4], rx[4];
    const unsigned* pm = part + (size_t)tm * NBP;
    const unsigned* px = part + (size_t)(TT + tm) * NBP;
    unsigned vmn = 0xFFFFFFFFu, vmx = 0u;
    for (int i = tid; i < NBP; i += 256) {
        vmn = min(vmn, pm[i]);
        vmx = max(vmx, px[i]);
    }
    #pragma unroll
    for (int off = 32; off; off >>= 1) {
        vmn = min(vmn, (unsigned)__shfl_xor((int)vmn, off, 64));
        vmx = max(vmx, (unsigned)__shfl_xor((int)vmx, off, 64));
    }
    if ((tid & 63) == 0) { rm[tid >> 6] = vmn; rx[tid >> 6] = vmx; }
    __syncthreads();
    vmn = min(min(rm[0], rm[1]), min(rm[2], rm[3]));
    vmx = max(max(rx[0], rx[1]), max(rx[2], rx[3]));
    float mn = decf(vmn);
    float mx = decf(vmx) - mn;
    float inv = fast_rcp((mx != 0.f) ? mx : 1e-5f);
    A  = inv;
    Bv = -mn * SUMW * inv;
}

// Pass 3: out[b,t] = (t<4) ? 0 : gs[b,t-4]*A + B; A/B reduced from partials inline.
__global__ __launch_bounds__(256) void k_pass3(const unsigned* __restrict__ gs,
                                               const unsigned* __restrict__ part,
                                               float* __restrict__ out) {
    const int bid = blockIdx.x;
    const int b   = bid / 476;             // 476 = 68*7
    const int r   = bid - b * 476;
    const int t   = r / 7;
    const int seg = r - t * 7;
    const int tid = threadIdx.x;
    const int base4 = seg * 1792 + tid;    // float4 index within frame
    float4* op = (float4*)out + ((size_t)b * 68 + t) * HW4 + base4;

    if (t < 4) {
        float4 z = make_float4(0.f, 0.f, 0.f, 0.f);
        #pragma unroll
        for (int k = 0; k < 7; ++k) op[k * 256] = z;
        return;
    }
    const int tm = t - 4;
    float A, Bv;
    reduce_part(part, tm, tid, A, Bv);

    const uint2* gpp = (const uint2*)gs + ((size_t)b * TT + tm) * HW4 + base4;
    #pragma unroll
    for (int k = 0; k < 7; ++k) {
        uint2 v = gpp[k * 256];
        union { unsigned u; _Float16 h[2]; } lo, hi; lo.u = v.x; hi.u = v.y;
        float4 o;
        o.x = fmaf((float)lo.h[0], A, Bv);
        o.y = fmaf((float)lo.h[1], A, Bv);
        o.z = fmaf((float)hi.h[0], A, Bv);
        o.w = fmaf((float)hi.h[1], A, Bv);
        op[k * 256] = o;
    }
}

// Fallback helpers (ws too small for gs): consts kernel + direct erf pass
__global__ __launch_bounds__(256) void k_consts(const unsigned* __restrict__ part,
                                                float* __restrict__ ab) {
    const int t = blockIdx.x;              // 64 blocks, one per t
    float A, Bv;
    reduce_part(part, t, threadIdx.x, A, Bv);
    if (threadIdx.x == 0) { ab[t] = A; ab[TT + t] = Bv; }
}

__global__ __launch_bounds__(256) void k_pass2_direct(const float* __restrict__ x,
                                                      const float* __restrict__ ab,
                                                      float* __restrict__ out) {
    __shared__ float sA[TT], sB[TT];
    const int tid = threadIdx.x;
    if (tid < TT)          sA[tid] = ab[tid];
    else if (tid < 2 * TT) sB[tid - TT] = ab[tid];
    __syncthreads();

    const int pix = blockIdx.x * 256 + tid;
    const int b  = pix / HW;
    const int hw = pix - b * HW;
    const float* x0 = x + (size_t)(b * 3) * (TT * (size_t)HW) + hw;
    const float* x1 = x0 + (size_t)TT * HW;
    const float* x2 = x1 + (size_t)TT * HW;
    float* op = out + (size_t)b * (68 * (size_t)HW) + hw;

    op[0] = 0.f; op[HW] = 0.f; op[2 * (size_t)HW] = 0.f; op[3 * (size_t)HW] = 0.f;
    op += 4 * (size_t)HW;

    float a0 = x0[0], a1 = x0[HW], a2 = x0[2*HW], a3 = x0[3*HW], a4 = x0[4*HW];
    float b0 = x1[0], b1 = x1[HW], b2 = x1[2*HW], b3 = x1[3*HW], b4 = x1[4*HW];
    float c0 = x2[0], c1 = x2[HW], c2 = x2[2*HW], c3 = x2[3*HW], c4 = x2[4*HW];

    auto emit = [&](int t, float ra, float rb, float rc) {
        float gsv = 0.2989f * gelu_erf(ra) + 0.587f * gelu_erf(rb) + 0.114f * gelu_erf(rc);
        op[(size_t)t * HW] = fmaf(gsv, sA[t], sB[t]);
    };

    for (int t = 0; t < 59; ++t) {
        emit(t, 4.f*(a4-a0) + 2.f*(a3-a1), 4.f*(b4-b0) + 2.f*(b3-b1), 4.f*(c4-c0) + 2.f*(c3-c1));
        a0=a1; a1=a2; a2=a3; a3=a4; a4 = x0[(size_t)(t+5)*HW];
        b0=b1; b1=b2; b2=b3; b3=b4; b4 = x1[(size_t)(t+5)*HW];
        c0=c1; c1=c2; c2=c3; c3=c4; c4 = x2[(size_t)(t+5)*HW];
    }
    emit(59, 4.f*(a4-a0) + 2.f*(a3-a1), 4.f*(b4-b0) + 2.f*(b3-b1), 4.f*(c4-c0) + 2.f*(c3-c1));
    a0=a1; a1=a2; a2=a3; a3=a4; b0=b1; b1=b2; b2=b3; b3=b4; c0=c1; c1=c2; c2=c3; c3=c4;
    emit(60, 3.f*(a3-a0) + (a2-a1), 3.f*(b3-b0) + (b2-b1), 3.f*(c3-c0) + (c2-c1));
    a0=a1; a1=a2; a2=a3; b0=b1; b1=b2; b2=b3; c0=c1; c1=c2; c2=c3;
    emit(61, 2.f*(a2-a0), 2.f*(b2-b0), 2.f*(c2-c0));
    a0=a1; a1=a2; b0=b1; b1=b2; c0=c1; c1=c2;
    emit(62, a1-a0, b1-b0, c1-c0);
    op[63 * (size_t)HW] = sB[63];
}

extern "C" void kernel_launch(void* const* d_in, const int* in_sizes, int n_in,
                              void* d_out, int out_size, void* d_ws, size_t ws_size,
                              hipStream_t stream) {
    const float* x = (const float*)d_in[0];
    float* out = (float*)d_out;
    // ws layout: [0,1024): ab (fallback); [1024, +401408): part (128 rows × 784);
    //            [402432, +51.4MB): gs
    float* ab = (float*)d_ws;
    unsigned* part = (unsigned*)((char*)d_ws + 1024);
    const size_t part_bytes = (size_t)2 * TT * NBP * 4;           // 401408
    unsigned* gs = (unsigned*)((char*)d_ws + 1024 + part_bytes);
    const size_t need = 1024 + part_bytes + (size_t)8 * TT * (size_t)HW2 * 4;  // ~51.8 MB

    if (ws_size >= need) {
        k_pass1<true><<<NBP, 256, 0, stream>>>(x, part, gs);
        k_pass3<<<3808, 256, 0, stream>>>(gs, part, out);
    } else if (ws_size >= 1024 + part_bytes) {
        k_pass1<false><<<NBP, 256, 0, stream>>>(x, part, nullptr);
        k_consts<<<TT, 256, 0, stream>>>(part, ab);
        k_pass2_direct<<<1568, 256, 0, stream>>>(x, ab, out);
    }
}